// Round 7
// baseline (211.525 us; speedup 1.0000x reference)
//
#include <hip/hip_runtime.h>
#include <math.h>

#define N_ 32
#define D_ 512
#define S_ 1600
#define K_ 64

typedef __attribute__((ext_vector_type(8))) short short8;   // 8 bf16 = 16 B (A/B frag)
typedef __attribute__((ext_vector_type(4))) float f32x4;    // acc frag

// float -> bf16 (round to nearest even), bit pattern in short
static __device__ __forceinline__ short f2bf(float f) {
    unsigned u = __float_as_uint(f);
    u += 0x7fffu + ((u >> 16) & 1u);
    return (short)(u >> 16);
}

// ---------------------------------------------------------------------------
// kW: conv_weight [64][512] fp32 -> bf16
// ---------------------------------------------------------------------------
__global__ __launch_bounds__(256) void kW(const float* __restrict__ w,
                                          short* __restrict__ w16)
{
    int i4 = (blockIdx.x * 256 + threadIdx.x) * 4;
    float4 v = *(const float4*)&w[i4];
    short4 h = {f2bf(v.x), f2bf(v.y), f2bf(v.z), f2bf(v.w)};
    *(short4*)&w16[i4] = h;
}

// ---------------------------------------------------------------------------
// kA: MFMA GEMM logits[k][s] = sum_d w16[k][d] * xbf[d][s] + fused softmax.
// 32-s tiles -> 1600 blocks (6.25 blocks/CU) for latency hiding (round-6 kA
// was grid-capped at 25% occupancy). Staging: thread = (s=tid&31, g0=tid>>5),
// per chunk 4x { 2 coalesced b32 x-loads -> pack 2xbf16 -> 1 b32 LDS write }.
// LDS write bank = (2s + r) % 32 -> 2 lanes/bank = free. Also emits x16[d][s]
// bf16 (for kB). ssq fp32 alongside.
//   aprime[n][k][s] = softmax_k * inv (bf16);  asum[n][k] += softmax (atomic)
// wave wv: k in [16wv,16wv+16), s = st*16+lk (st=0,1).
// D[row=4q+r <- k (A op)][col=lk <- s (B op)]  (round-4/6 verified).
// ---------------------------------------------------------------------------
__global__ __launch_bounds__(256) void kA(const float* __restrict__ x,
                                          const short* __restrict__ w16,
                                          short* __restrict__ x16,
                                          short* __restrict__ aprime,
                                          float* __restrict__ asum)
{
    __shared__ unsigned Tw[32 * 34];    // [s][d-pair r] ; as shorts: pitch 68
    __shared__ float pssq[8][32];
    __shared__ float invL[32];
    __shared__ float wred[2][4][32];

    const int tid = threadIdx.x;
    const int n  = blockIdx.x / 50;
    const int s0 = (blockIdx.x % 50) * 32;
    const int wv = tid >> 6;
    const int l  = tid & 63;
    const int lk = l & 15;
    const int q  = l >> 4;
    const int sl = tid & 31;     // staging s-col
    const int g0 = tid >> 5;     // staging d-pair group 0..7

    const float* xb = x + (size_t)n * D_ * S_ + s0 + sl;
    short* x16b = x16 + (size_t)n * D_ * S_ + s0 + sl;

    f32x4 acc[2];
    acc[0] = (f32x4){0.f, 0.f, 0.f, 0.f};
    acc[1] = (f32x4){0.f, 0.f, 0.f, 0.f};
    float ssl = 0.f;

    for (int dc = 0; dc < D_; dc += 64) {
        __syncthreads();
#pragma unroll
        for (int j = 0; j < 4; ++j) {
            const int r = g0 + 8 * j;                    // d-pair 0..31
            float v0 = xb[(size_t)(dc + 2 * r) * S_];
            float v1 = xb[(size_t)(dc + 2 * r + 1) * S_];
            ssl += v0 * v0 + v1 * v1;
            unsigned lo = (unsigned short)f2bf(v0);
            unsigned hi = (unsigned short)f2bf(v1);
            Tw[sl * 34 + r] = lo | (hi << 16);           // bank=(2s+r)%32: 2-way
            x16b[(size_t)(dc + 2 * r) * S_]     = (short)lo;
            x16b[(size_t)(dc + 2 * r + 1) * S_] = (short)hi;
        }
        __syncthreads();

        const short* T = (const short*)Tw;
#pragma unroll
        for (int kst = 0; kst < 2; ++kst) {
            short8 af = *(const short8*)&w16[(16 * wv + lk) * D_ + dc + kst * 32 + q * 8];
#pragma unroll
            for (int st = 0; st < 2; ++st) {
                const short* bp = &T[(st * 16 + lk) * 68 + kst * 32 + q * 8];
                short4 b0 = *(const short4*)bp;
                short4 b1 = *(const short4*)(bp + 4);
                short8 bf = {b0.x, b0.y, b0.z, b0.w, b1.x, b1.y, b1.z, b1.w};
                acc[st] = __builtin_amdgcn_mfma_f32_16x16x32_bf16(af, bf, acc[st], 0, 0, 0);
            }
        }
    }

    // inv = 1/||x_s||: 8 threads per s (tid>>5 groups) each covered 64 d
    __syncthreads();
    pssq[g0][sl] = ssl;
    __syncthreads();
    if (tid < 32) {
        float ss = 0.f;
#pragma unroll
        for (int g = 0; g < 8; ++g) ss += pssq[g][tid];
        invL[tid] = 1.0f / fmaxf(sqrtf(ss), 1e-12f);
    }
    __syncthreads();

    // epilogue: softmax over k (64 = 4r x 4q x 4wv) per s-column (st,lk)
    float lg[2][4], invv[2];
#pragma unroll
    for (int st = 0; st < 2; ++st) {
        invv[st] = invL[st * 16 + lk];
#pragma unroll
        for (int r = 0; r < 4; ++r) lg[st][r] = acc[st][r] * invv[st];
    }
#pragma unroll
    for (int st = 0; st < 2; ++st) {
        float m = fmaxf(fmaxf(lg[st][0], lg[st][1]), fmaxf(lg[st][2], lg[st][3]));
        m = fmaxf(m, __shfl_xor(m, 16));
        m = fmaxf(m, __shfl_xor(m, 32));
        if (q == 0) wred[0][wv][st * 16 + lk] = m;
    }
    __syncthreads();
    float gm[2];
#pragma unroll
    for (int st = 0; st < 2; ++st) {
        float m = wred[0][0][st * 16 + lk];
        m = fmaxf(m, wred[0][1][st * 16 + lk]);
        m = fmaxf(m, wred[0][2][st * 16 + lk]);
        m = fmaxf(m, wred[0][3][st * 16 + lk]);
        gm[st] = m;
    }
    float e[2][4];
#pragma unroll
    for (int st = 0; st < 2; ++st) {
        float s = 0.f;
#pragma unroll
        for (int r = 0; r < 4; ++r) {
            e[st][r] = __expf(lg[st][r] - gm[st]);
            s += e[st][r];
        }
        s += __shfl_xor(s, 16);
        s += __shfl_xor(s, 32);
        if (q == 0) wred[1][wv][st * 16 + lk] = s;
    }
    __syncthreads();
    float rs[2];
#pragma unroll
    for (int st = 0; st < 2; ++st) {
        float s = wred[1][0][st * 16 + lk] + wred[1][1][st * 16 + lk]
                + wred[1][2][st * 16 + lk] + wred[1][3][st * 16 + lk];
        rs[st] = 1.0f / s;
    }

    short* apb = aprime + (size_t)n * K_ * S_ + s0;
#pragma unroll
    for (int r = 0; r < 4; ++r) {
        const int k = 16 * wv + 4 * q + r;
        float accp = 0.f;
#pragma unroll
        for (int st = 0; st < 2; ++st) {
            float p = e[st][r] * rs[st];
            apb[(size_t)k * S_ + st * 16 + lk] = f2bf(p * invv[st]);
            accp += p;
        }
        accp += __shfl_xor(accp, 1);
        accp += __shfl_xor(accp, 2);
        accp += __shfl_xor(accp, 4);
        accp += __shfl_xor(accp, 8);
        if (lk == 0) atomicAdd(&asum[n * K_ + k], accp);
    }
}

// ---------------------------------------------------------------------------
// kB: LDS-free MFMA GEMM. agg[k][d] partial over s-split:
//   agg[k][d] = sum_s aprime[k][s] * x16[d][s]   (both bf16, s-contiguous)
// grid: n(32) x dtile(4 of 128) x split(10 of 160s) = 1280 blocks x 256 thr.
// ---------------------------------------------------------------------------
__global__ __launch_bounds__(256) void kB(const short* __restrict__ x16,
                                          const short* __restrict__ aprime,
                                          float* __restrict__ aggp)
{
    const int bid = blockIdx.x;
    const int n  = bid / 40;
    const int dt = (bid % 40) / 10;
    const int sp = bid % 10;
    const int wv = threadIdx.x >> 6;
    const int l  = threadIdx.x & 63;
    const int lk = l & 15;
    const int q  = l >> 4;
    const int dbase = dt * 128 + wv * 32;

    const short* ap = aprime + (size_t)n * K_ * S_;
    const short* xb = x16 + (size_t)n * D_ * S_;

    f32x4 acc[4][2];
#pragma unroll
    for (int kt = 0; kt < 4; ++kt)
#pragma unroll
        for (int ds = 0; ds < 2; ++ds) acc[kt][ds] = (f32x4){0.f, 0.f, 0.f, 0.f};

#pragma unroll
    for (int kst = 0; kst < 5; ++kst) {
        const int s = sp * 160 + kst * 32 + q * 8;
        short8 af[4];
#pragma unroll
        for (int kt = 0; kt < 4; ++kt)
            af[kt] = *(const short8*)&ap[(size_t)(kt * 16 + lk) * S_ + s];
        short8 bf[2];
#pragma unroll
        for (int ds = 0; ds < 2; ++ds)
            bf[ds] = *(const short8*)&xb[(size_t)(dbase + ds * 16 + lk) * S_ + s];
#pragma unroll
        for (int kt = 0; kt < 4; ++kt)
#pragma unroll
            for (int ds = 0; ds < 2; ++ds)
                acc[kt][ds] = __builtin_amdgcn_mfma_f32_16x16x32_bf16(af[kt], bf[ds], acc[kt][ds], 0, 0, 0);
    }

    float* ab = aggp + ((size_t)sp * N_ + n) * K_ * D_;
#pragma unroll
    for (int kt = 0; kt < 4; ++kt)
#pragma unroll
        for (int ds = 0; ds < 2; ++ds)
#pragma unroll
            for (int r = 0; r < 4; ++r)
                ab[(size_t)(kt * 16 + 4 * q + r) * D_ + dbase + ds * 16 + lk] = acc[kt][ds][r];
}

// ---------------------------------------------------------------------------
// kC: vlad = (sum of 10 agg partials) - asum*centroid; intra-L2-norm over d;
// global norm = /sqrt(K) = /8 exactly. grid: 2048 blocks x 256 thr.
// ---------------------------------------------------------------------------
__global__ __launch_bounds__(256) void kC(const float* __restrict__ aggp,
                                          const float* __restrict__ asum,
                                          const float* __restrict__ cent,
                                          float* __restrict__ out)
{
    __shared__ float red[4];
    const int tid = threadIdx.x;
    const int nk = blockIdx.x;
    const int k = nk & 63;
    const float as = asum[nk];
    const float* cb = cent + (size_t)k * D_;

    float v0 = 0.f, v1 = 0.f;
#pragma unroll
    for (int p = 0; p < 10; ++p) {
        const float* ag = aggp + (size_t)p * N_ * K_ * D_ + (size_t)nk * D_;
        v0 += ag[tid];
        v1 += ag[tid + 256];
    }
    v0 -= as * cb[tid];
    v1 -= as * cb[tid + 256];
    float ssq = v0 * v0 + v1 * v1;

    ssq += __shfl_xor(ssq, 32);
    ssq += __shfl_xor(ssq, 16);
    ssq += __shfl_xor(ssq, 8);
    ssq += __shfl_xor(ssq, 4);
    ssq += __shfl_xor(ssq, 2);
    ssq += __shfl_xor(ssq, 1);
    if ((tid & 63) == 0) red[tid >> 6] = ssq;
    __syncthreads();
    const float total = red[0] + red[1] + red[2] + red[3];
    const float scale = 1.0f / (fmaxf(sqrtf(total), 1e-12f) * 8.0f);

    out[(size_t)nk * D_ + tid]       = v0 * scale;
    out[(size_t)nk * D_ + tid + 256] = v1 * scale;
}

// ---------------------------------------------------------------------------
extern "C" void kernel_launch(void* const* d_in, const int* in_sizes, int n_in,
                              void* d_out, int out_size, void* d_ws, size_t ws_size,
                              hipStream_t stream)
{
    const float* x    = (const float*)d_in[0];   // [32,512,40,40]
    const float* w    = (const float*)d_in[1];   // [64,512]
    const float* cent = (const float*)d_in[2];   // [64,512]
    float* out = (float*)d_out;                  // [32, 32768]

    // ws carve (~97 MB), fp32 first, all 16B-aligned
    float* aggp   = (float*)d_ws;                          // 10*N*K*D fp32
    float* asum   = aggp + (size_t)10 * N_ * K_ * D_;      // N*K fp32
    short* aprime = (short*)(asum + N_ * K_);              // N*K*S bf16
    short* w16    = aprime + (size_t)N_ * K_ * S_;         // K*D bf16
    short* x16    = w16 + (size_t)K_ * D_;                 // N*D*S bf16

    hipMemsetAsync(asum, 0, (size_t)N_ * K_ * sizeof(float), stream);

    kW<<<32, 256, 0, stream>>>(w, w16);
    kA<<<N_ * (S_ / 32), 256, 0, stream>>>(x, w16, x16, aprime, asum);
    kB<<<N_ * 4 * 10, 256, 0, stream>>>(x16, aprime, aggp);
    kC<<<N_ * K_, 256, 0, stream>>>(aggp, asum, cent, out);
}